// Round 5
// baseline (873.769 us; speedup 1.0000x reference)
//
#include <hip/hip_runtime.h>
#include <hip/hip_bf16.h>

#define NF 22     // node features
#define H  32     // hidden dim
#define BSH 8     // bucket shift: 256 nodes per bucket
#define CHUNK 4096
// NB = ceil(N/256) = 391 for N=100k; LDS arrays sized 512 (requires N <= 131072)

// ---- zero small int array ----
__global__ void zero_ints(int* __restrict__ p, int n) {
    int i = blockIdx.x * blockDim.x + threadIdx.x;
    if (i < n) p[i] = 0;
}

// ---- per-bucket histogram with LDS pre-aggregation ----
__global__ __launch_bounds__(256) void bucket_hist(
    const int* __restrict__ dst, int* __restrict__ bcnt, int E, int NB)
{
    __shared__ int lh[512];
    int tid = threadIdx.x;
    for (int j = tid; j < NB; j += 256) lh[j] = 0;
    __syncthreads();
    int e0 = blockIdx.x * CHUNK;
    int ee = min(e0 + CHUNK, E);
    for (int i = e0 + tid; i < ee; i += 256) atomicAdd(&lh[dst[i] >> BSH], 1);
    __syncthreads();
    for (int j = tid; j < NB; j += 256) {
        int c = lh[j];
        if (c) atomicAdd(&bcnt[j], c);
    }
}

// ---- exclusive scan of bucket counts (single WG, 512 threads) ----
__global__ __launch_bounds__(512) void bucket_scan(
    const int* __restrict__ bcnt, int* __restrict__ base, int* __restrict__ cursor, int NB)
{
    __shared__ int s[512];
    int tid = threadIdx.x;
    s[tid] = (tid < NB) ? bcnt[tid] : 0;
    __syncthreads();
    for (int off = 1; off < 512; off <<= 1) {
        int t = (tid >= off) ? s[tid - off] : 0;
        __syncthreads();
        s[tid] += t;
        __syncthreads();
    }
    if (tid < NB) {
        int b = (tid > 0) ? s[tid - 1] : 0;
        base[tid] = b;
        cursor[tid] = b;
    }
}

// ---- bin edges by dst bucket; per-WG two-phase reservation for dense writes ----
__global__ __launch_bounds__(256) void bin_edges(
    const int* __restrict__ src, const int* __restrict__ dst,
    int* __restrict__ cursor, int2* __restrict__ binned, int E, int NB)
{
    __shared__ int lh[512];
    __shared__ int lcur[512];
    int tid = threadIdx.x;
    for (int j = tid; j < NB; j += 256) lh[j] = 0;
    __syncthreads();
    int e0 = blockIdx.x * CHUNK;
    int ee = min(e0 + CHUNK, E);
    for (int i = e0 + tid; i < ee; i += 256) atomicAdd(&lh[dst[i] >> BSH], 1);
    __syncthreads();
    for (int j = tid; j < NB; j += 256) {
        int c = lh[j];
        if (c) lcur[j] = atomicAdd(&cursor[j], c);  // reserve contiguous range
    }
    __syncthreads();
    for (int i = e0 + tid; i < ee; i += 256) {
        int d = dst[i];
        int p = atomicAdd(&lcur[d >> BSH], 1);      // LDS atomic, returns global slot
        binned[p] = make_int2(src[i], d);
    }
}

// ---- per-node degree (from binned) -> dis = rsqrt(deg+1) ----
__global__ __launch_bounds__(256) void deg_dis(
    const int* __restrict__ base, const int* __restrict__ bcnt,
    const int2* __restrict__ binned, float* __restrict__ dis, int N)
{
    __shared__ int cnt[256];
    int b = blockIdx.x, tid = threadIdx.x;
    int bn = b << BSH;
    cnt[tid] = 0;
    __syncthreads();
    int es = base[b], ee = es + bcnt[b];
    for (int i = es + tid; i < ee; i += 256) atomicAdd(&cnt[binned[i].y - bn], 1);
    __syncthreads();
    int n = bn + tid;
    if (n < N) dis[n] = rsqrtf((float)(cnt[tid] + 1));
}

// ---- h0 = x@We + be ; g1 = dis * (h0@W1) ----
__global__ __launch_bounds__(256) void embed_g1(
    const float* __restrict__ x, const float* __restrict__ We,
    const float* __restrict__ be, const float* __restrict__ W1,
    const float* __restrict__ dis, float* __restrict__ h0,
    float* __restrict__ g, int N)
{
    __shared__ float sWe[NF * H];
    __shared__ float sW1[H * H];
    __shared__ float sbe[H];
    __shared__ float sx[8][NF];
    __shared__ float sh[8][H];

    int tid = threadIdx.x;
    for (int j = tid; j < NF * H; j += 256) sWe[j] = We[j];
    for (int j = tid; j < H * H; j += 256) sW1[j] = W1[j];
    if (tid < H) sbe[tid] = be[tid];

    int grp = tid >> 5, t = tid & 31;
    int node = blockIdx.x * 8 + grp;
    int nodec = node < N ? node : N - 1;
    if (t < NF) sx[grp][t] = x[(size_t)nodec * NF + t];
    __syncthreads();

    float h = sbe[t];
#pragma unroll
    for (int k = 0; k < NF; k++) h += sx[grp][k] * sWe[k * H + t];
    sh[grp][t] = h;
    __syncthreads();

    float gv = 0.f;
#pragma unroll
    for (int k = 0; k < H; k++) gv += sh[grp][k] * sW1[k * H + t];
    gv *= dis[nodec];

    if (node < N) {
        size_t o = (size_t)node * H + t;
        h0[o] = h;
        g[o] = gv;
    }
}

// ---- LDS-tile aggregation: acc[d] = g[d] + sum_{s->d} g[s], no global atomics ----
__global__ __launch_bounds__(256) void agg_lds(
    const int* __restrict__ base, const int* __restrict__ bcnt,
    const int2* __restrict__ binned, const float* __restrict__ g,
    float* __restrict__ acc, int N)
{
    __shared__ float tile[256 * H];   // 32 KB
    int b = blockIdx.x, tid = threadIdx.x;
    int bn = b << BSH;
    for (int j = tid; j < 256 * H; j += 256) tile[j] = 0.f;
    __syncthreads();

    int es = base[b], ee = es + bcnt[b];
    int c = tid & 31;
    int i = es + (tid >> 5);
    // 2-way unrolled: two gathers in flight per thread
    for (; i + 8 < ee; i += 16) {
        int2 e0 = binned[i];
        int2 e1 = binned[i + 8];
        float g0 = g[(size_t)e0.x * H + c];
        float g1 = g[(size_t)e1.x * H + c];
        atomicAdd(&tile[((e0.y - bn) << 5) + c], g0);
        atomicAdd(&tile[((e1.y - bn) << 5) + c], g1);
    }
    if (i < ee) {
        int2 e0 = binned[i];
        atomicAdd(&tile[((e0.y - bn) << 5) + c], g[(size_t)e0.x * H + c]);
    }
    __syncthreads();

    int nmax = min(256, N - bn);
    for (int n = tid >> 5; n < nmax; n += 8) {
        size_t o = (size_t)(bn + n) * H + c;
        acc[o] = tile[(n << 5) + c] + g[o];   // + self-loop term
    }
}

// ---- r1 = relu(dis*acc + b1); g2 = dis * ([r1,h0]@W2) ----
__global__ __launch_bounds__(256) void mid_g2(
    const float* __restrict__ W2, const float* __restrict__ b1,
    const float* __restrict__ dis, const float* __restrict__ h0,
    float* __restrict__ g, const float* __restrict__ acc, int N)
{
    __shared__ float sW2[2 * H * H];
    __shared__ float sb1[H];
    __shared__ float srow[8][2 * H];

    int tid = threadIdx.x;
    for (int j = tid; j < 2 * H * H; j += 256) sW2[j] = W2[j];
    if (tid < H) sb1[tid] = b1[tid];
    __syncthreads();

    int grp = tid >> 5, t = tid & 31;
    int node = blockIdx.x * 8 + grp;
    int nodec = node < N ? node : N - 1;
    size_t o = (size_t)nodec * H + t;

    float di = dis[nodec];
    float r = fmaxf(di * acc[o] + sb1[t], 0.f);
    srow[grp][t] = r;
    srow[grp][H + t] = h0[o];
    __syncthreads();

    float gv = 0.f;
#pragma unroll
    for (int k = 0; k < 2 * H; k++) gv += srow[grp][k] * sW2[k * H + t];
    gv *= di;

    if (node < N) g[(size_t)node * H + t] = gv;
}

// ---- out = relu([relu(dis*acc+b2), h0] @ Wp + bp + x[:,1]) ----
__global__ __launch_bounds__(256) void final_pred(
    const float* __restrict__ acc, const float* __restrict__ h0,
    const float* __restrict__ dis, const float* __restrict__ b2,
    const float* __restrict__ Wp, const float* __restrict__ bp,
    const float* __restrict__ x, float* __restrict__ out, int N)
{
    int i = blockIdx.x * blockDim.x + threadIdx.x;
    if (i >= N) return;
    float di = dis[i];
    float a = bp[0] + x[(size_t)i * NF + 1];
    size_t o = (size_t)i * H;
#pragma unroll
    for (int c = 0; c < H; c++)
        a += fmaxf(di * acc[o + c] + b2[c], 0.f) * Wp[c];
#pragma unroll
    for (int c = 0; c < H; c++)
        a += h0[o + c] * Wp[H + c];
    out[i] = fmaxf(a, 0.f);
}

extern "C" void kernel_launch(void* const* d_in, const int* in_sizes, int n_in,
                              void* d_out, int out_size, void* d_ws, size_t ws_size,
                              hipStream_t stream) {
    const float* x  = (const float*)d_in[0];
    const int*   ei = (const int*)d_in[1];
    const float* We = (const float*)d_in[2];
    const float* be = (const float*)d_in[3];
    const float* W1 = (const float*)d_in[4];
    const float* b1 = (const float*)d_in[5];
    const float* W2 = (const float*)d_in[6];
    const float* b2 = (const float*)d_in[7];
    const float* Wp = (const float*)d_in[8];
    const float* bp = (const float*)d_in[9];
    float* out = (float*)d_out;

    const int N = in_sizes[0] / NF;
    const int E = in_sizes[1] / 2;
    const int* src = ei;
    const int* dst = ei + E;
    const int NB = (N + 255) >> BSH;            // 391 buckets
    const int nchunk = (E + CHUNK - 1) / CHUNK; // 391 chunks

    // workspace layout
    size_t Np  = ((size_t)N + 127) & ~(size_t)127;
    size_t NHp = ((size_t)N * H + 127) & ~(size_t)127;
    float* ws  = (float*)d_ws;
    float* dis = ws;                    // Np
    float* h0  = dis + Np;              // NHp
    float* g   = h0 + NHp;              // NHp
    float* acc = g + NHp;               // NHp
    int* bcnt   = (int*)(acc + NHp);    // 512
    int* bbase  = bcnt + 512;           // 512
    int* bcur   = bbase + 512;          // 512
    int2* binned = (int2*)(bcur + 512); // E int2

    zero_ints<<<2, 256, 0, stream>>>(bcnt, NB);
    bucket_hist<<<nchunk, 256, 0, stream>>>(dst, bcnt, E, NB);
    bucket_scan<<<1, 512, 0, stream>>>(bcnt, bbase, bcur, NB);
    bin_edges<<<nchunk, 256, 0, stream>>>(src, dst, bcur, binned, E, NB);
    deg_dis<<<NB, 256, 0, stream>>>(bbase, bcnt, binned, dis, N);

    embed_g1<<<(N + 7) / 8, 256, 0, stream>>>(x, We, be, W1, dis, h0, g, N);
    agg_lds<<<NB, 256, 0, stream>>>(bbase, bcnt, binned, g, acc, N);
    mid_g2<<<(N + 7) / 8, 256, 0, stream>>>(W2, b1, dis, h0, g, acc, N);
    agg_lds<<<NB, 256, 0, stream>>>(bbase, bcnt, binned, g, acc, N);
    final_pred<<<(N + 255) / 256, 256, 0, stream>>>(acc, h0, dis, b2, Wp, bp, x, out, N);
}

// Round 6
// 269.267 us; speedup vs baseline: 3.2450x; 3.2450x over previous
//
#include <hip/hip_runtime.h>
#include <hip/hip_bf16.h>

#define NF 22     // node features
#define H  32     // hidden dim
#define BSH 8     // 256 nodes per bucket
#define CHUNK 4096
// NB = ceil(N/256) = 391 for N=100k; requires N <= 131072 (src fits 17 bits)

__global__ void zero_ints(int* __restrict__ p, int n) {
    int i = blockIdx.x * blockDim.x + threadIdx.x;
    if (i < n) p[i] = 0;
}

__global__ void set_int(int* __restrict__ p, int v) { *p = v; }

// ---- per-bucket histogram with LDS pre-aggregation ----
__global__ __launch_bounds__(256) void bucket_hist(
    const int* __restrict__ dst, int* __restrict__ bcnt, int E, int NB)
{
    __shared__ int lh[512];
    int tid = threadIdx.x;
    for (int j = tid; j < NB; j += 256) lh[j] = 0;
    __syncthreads();
    int e0 = blockIdx.x * CHUNK;
    int ee = min(e0 + CHUNK, E);
    for (int i = e0 + tid; i < ee; i += 256) atomicAdd(&lh[dst[i] >> BSH], 1);
    __syncthreads();
    for (int j = tid; j < NB; j += 256) {
        int c = lh[j];
        if (c) atomicAdd(&bcnt[j], c);
    }
}

// ---- exclusive scan of bucket counts (single WG); base has NB+1 entries ----
__global__ __launch_bounds__(512) void bucket_scan(
    const int* __restrict__ bcnt, int* __restrict__ base, int* __restrict__ cursor,
    int NB, int E)
{
    __shared__ int s[512];
    int tid = threadIdx.x;
    s[tid] = (tid < NB) ? bcnt[tid] : 0;
    __syncthreads();
    for (int off = 1; off < 512; off <<= 1) {
        int t = (tid >= off) ? s[tid - off] : 0;
        __syncthreads();
        s[tid] += t;
        __syncthreads();
    }
    if (tid < NB) {
        int b = (tid > 0) ? s[tid - 1] : 0;
        base[tid] = b;
        cursor[tid] = b;
    }
    if (tid == 0) base[NB] = E;
}

// ---- bin edges by dst bucket; packed (src<<8)|(dst&255); dense reserved writes ----
__global__ __launch_bounds__(256) void bin_edges(
    const int* __restrict__ src, const int* __restrict__ dst,
    int* __restrict__ cursor, int* __restrict__ binned, int E, int NB)
{
    __shared__ int lh[512];
    __shared__ int lcur[512];
    int tid = threadIdx.x;
    for (int j = tid; j < NB; j += 256) lh[j] = 0;
    __syncthreads();
    int e0 = blockIdx.x * CHUNK;
    int ee = min(e0 + CHUNK, E);
    for (int i = e0 + tid; i < ee; i += 256) atomicAdd(&lh[dst[i] >> BSH], 1);
    __syncthreads();
    for (int j = tid; j < NB; j += 256) {
        int c = lh[j];
        if (c) lcur[j] = atomicAdd(&cursor[j], c);  // reserve contiguous range
    }
    __syncthreads();
    for (int i = e0 + tid; i < ee; i += 256) {
        int d = dst[i];
        int p = atomicAdd(&lcur[d >> BSH], 1);      // LDS atomic -> global slot
        binned[p] = (src[i] << BSH) | (d & 255);
    }
}

// ---- per-bucket CSR: per-node rowptr + within-bucket dst-sort of src; dis ----
__global__ __launch_bounds__(256) void bucket_csr(
    const int* __restrict__ base, const int* __restrict__ binned,
    int* __restrict__ rowptr, int* __restrict__ sorted_src,
    float* __restrict__ dis, int N)
{
    __shared__ int cnt[256];
    __shared__ int s[256];
    __shared__ int lcur[256];
    int b = blockIdx.x, tid = threadIdx.x;
    int bn = b << BSH;
    cnt[tid] = 0;
    __syncthreads();
    int es = base[b], ee = base[b + 1];
    for (int i = es + tid; i < ee; i += 256) atomicAdd(&cnt[binned[i] & 255], 1);
    __syncthreads();
    int v = cnt[tid];
    s[tid] = v;
    __syncthreads();
    for (int off = 1; off < 256; off <<= 1) {
        int t = (tid >= off) ? s[tid - off] : 0;
        __syncthreads();
        s[tid] += t;
        __syncthreads();
    }
    int ex = s[tid] - v;   // exclusive scan
    lcur[tid] = ex;
    int n = bn + tid;
    if (n < N) {
        rowptr[n] = es + ex;
        dis[n] = rsqrtf((float)(v + 1));
    }
    __syncthreads();
    // scatter src into this bucket's contiguous range (single-WG-owned lines)
    for (int i = es + tid; i < ee; i += 256) {
        int e = binned[i];
        int p = atomicAdd(&lcur[e & 255], 1);
        sorted_src[es + p] = e >> BSH;
    }
}

// ---- h0 = x@We + be ; g1 = dis * (h0@W1) ----
__global__ __launch_bounds__(256) void embed_g1(
    const float* __restrict__ x, const float* __restrict__ We,
    const float* __restrict__ be, const float* __restrict__ W1,
    const float* __restrict__ dis, float* __restrict__ h0,
    float* __restrict__ g, int N)
{
    __shared__ float sWe[NF * H];
    __shared__ float sW1[H * H];
    __shared__ float sbe[H];
    __shared__ float sx[8][NF];
    __shared__ float sh[8][H];

    int tid = threadIdx.x;
    for (int j = tid; j < NF * H; j += 256) sWe[j] = We[j];
    for (int j = tid; j < H * H; j += 256) sW1[j] = W1[j];
    if (tid < H) sbe[tid] = be[tid];

    int grp = tid >> 5, t = tid & 31;
    int node = blockIdx.x * 8 + grp;
    int nodec = node < N ? node : N - 1;
    if (t < NF) sx[grp][t] = x[(size_t)nodec * NF + t];
    __syncthreads();

    float h = sbe[t];
#pragma unroll
    for (int k = 0; k < NF; k++) h += sx[grp][k] * sWe[k * H + t];
    sh[grp][t] = h;
    __syncthreads();

    float gv = 0.f;
#pragma unroll
    for (int k = 0; k < H; k++) gv += sh[grp][k] * sW1[k * H + t];
    gv *= dis[nodec];

    if (node < N) {
        size_t o = (size_t)node * H + t;
        h0[o] = h;
        g[o] = gv;
    }
}

// ---- atomic-free node-parallel aggregation: acc[d] = g[d] + sum g[src] ----
__global__ __launch_bounds__(256) void gather_agg(
    const int* __restrict__ rowptr, const int* __restrict__ sorted_src,
    const float* __restrict__ g, float* __restrict__ acc, int N)
{
    int gid = blockIdx.x * blockDim.x + threadIdx.x;
    int node = gid >> 5;
    if (node >= N) return;
    int c = gid & 31;
    int start = rowptr[node];
    int end = rowptr[node + 1];
    float a = g[(size_t)node * H + c];  // self-loop term
    int i = start;
    for (; i + 3 < end; i += 4) {
        int s0 = sorted_src[i], s1 = sorted_src[i + 1];
        int s2 = sorted_src[i + 2], s3 = sorted_src[i + 3];
        a += g[(size_t)s0 * H + c];
        a += g[(size_t)s1 * H + c];
        a += g[(size_t)s2 * H + c];
        a += g[(size_t)s3 * H + c];
    }
    for (; i < end; i++) a += g[(size_t)sorted_src[i] * H + c];
    acc[(size_t)node * H + c] = a;
}

// ---- r1 = relu(dis*acc + b1); g2 = dis * ([r1,h0]@W2) ----
__global__ __launch_bounds__(256) void mid_g2(
    const float* __restrict__ W2, const float* __restrict__ b1,
    const float* __restrict__ dis, const float* __restrict__ h0,
    float* __restrict__ g, const float* __restrict__ acc, int N)
{
    __shared__ float sW2[2 * H * H];
    __shared__ float sb1[H];
    __shared__ float srow[8][2 * H];

    int tid = threadIdx.x;
    for (int j = tid; j < 2 * H * H; j += 256) sW2[j] = W2[j];
    if (tid < H) sb1[tid] = b1[tid];
    __syncthreads();

    int grp = tid >> 5, t = tid & 31;
    int node = blockIdx.x * 8 + grp;
    int nodec = node < N ? node : N - 1;
    size_t o = (size_t)nodec * H + t;

    float di = dis[nodec];
    float r = fmaxf(di * acc[o] + sb1[t], 0.f);
    srow[grp][t] = r;
    srow[grp][H + t] = h0[o];
    __syncthreads();

    float gv = 0.f;
#pragma unroll
    for (int k = 0; k < 2 * H; k++) gv += srow[grp][k] * sW2[k * H + t];
    gv *= di;

    if (node < N) g[(size_t)node * H + t] = gv;
}

// ---- out = relu([relu(dis*acc+b2), h0] @ Wp + bp + x[:,1]) ----
__global__ __launch_bounds__(256) void final_pred(
    const float* __restrict__ acc, const float* __restrict__ h0,
    const float* __restrict__ dis, const float* __restrict__ b2,
    const float* __restrict__ Wp, const float* __restrict__ bp,
    const float* __restrict__ x, float* __restrict__ out, int N)
{
    int i = blockIdx.x * blockDim.x + threadIdx.x;
    if (i >= N) return;
    float di = dis[i];
    float a = bp[0] + x[(size_t)i * NF + 1];
    size_t o = (size_t)i * H;
#pragma unroll
    for (int c = 0; c < H; c++)
        a += fmaxf(di * acc[o + c] + b2[c], 0.f) * Wp[c];
#pragma unroll
    for (int c = 0; c < H; c++)
        a += h0[o + c] * Wp[H + c];
    out[i] = fmaxf(a, 0.f);
}

extern "C" void kernel_launch(void* const* d_in, const int* in_sizes, int n_in,
                              void* d_out, int out_size, void* d_ws, size_t ws_size,
                              hipStream_t stream) {
    const float* x  = (const float*)d_in[0];
    const int*   ei = (const int*)d_in[1];
    const float* We = (const float*)d_in[2];
    const float* be = (const float*)d_in[3];
    const float* W1 = (const float*)d_in[4];
    const float* b1 = (const float*)d_in[5];
    const float* W2 = (const float*)d_in[6];
    const float* b2 = (const float*)d_in[7];
    const float* Wp = (const float*)d_in[8];
    const float* bp = (const float*)d_in[9];
    float* out = (float*)d_out;

    const int N = in_sizes[0] / NF;
    const int E = in_sizes[1] / 2;
    const int* src = ei;
    const int* dst = ei + E;
    const int NB = (N + 255) >> BSH;            // 391
    const int nchunk = (E + CHUNK - 1) / CHUNK; // 391

    // workspace layout
    size_t Np  = ((size_t)N + 127) & ~(size_t)127;
    size_t NHp = ((size_t)N * H + 127) & ~(size_t)127;
    size_t Ep  = ((size_t)E + 127) & ~(size_t)127;
    float* ws  = (float*)d_ws;
    float* dis = ws;                    // Np
    float* h0  = dis + Np;              // NHp
    float* g   = h0 + NHp;              // NHp
    float* acc = g + NHp;               // NHp
    int* bcnt       = (int*)(acc + NHp);  // 512
    int* bbase      = bcnt + 512;         // 1024 (NB+1)
    int* bcur       = bbase + 1024;       // 512
    int* rowptr     = bcur + 512;         // Np + 128 (N+1)
    int* binned     = rowptr + Np + 128;  // Ep
    int* sorted_src = binned + Ep;        // Ep

    zero_ints<<<2, 256, 0, stream>>>(bcnt, NB);
    bucket_hist<<<nchunk, 256, 0, stream>>>(dst, bcnt, E, NB);
    bucket_scan<<<1, 512, 0, stream>>>(bcnt, bbase, bcur, NB, E);
    set_int<<<1, 1, 0, stream>>>(rowptr + N, E);
    bin_edges<<<nchunk, 256, 0, stream>>>(src, dst, bcur, binned, E, NB);
    bucket_csr<<<NB, 256, 0, stream>>>(bbase, binned, rowptr, sorted_src, dis, N);

    embed_g1<<<(N + 7) / 8, 256, 0, stream>>>(x, We, be, W1, dis, h0, g, N);
    gather_agg<<<((size_t)N * 32 + 255) / 256, 256, 0, stream>>>(rowptr, sorted_src, g, acc, N);
    mid_g2<<<(N + 7) / 8, 256, 0, stream>>>(W2, b1, dis, h0, g, acc, N);
    gather_agg<<<((size_t)N * 32 + 255) / 256, 256, 0, stream>>>(rowptr, sorted_src, g, acc, N);
    final_pred<<<(N + 255) / 256, 256, 0, stream>>>(acc, h0, dis, b2, Wp, bp, x, out, N);
}

// Round 7
// 258.484 us; speedup vs baseline: 3.3804x; 1.0417x over previous
//
#include <hip/hip_runtime.h>
#include <hip/hip_bf16.h>

#define NF 22     // node features
#define H  32     // hidden dim
#define BSH 8     // 256 nodes per bucket
#define CAP 8192  // edge capacity per bucket (mean 4092 at E=1.6M, NB=391; +60 sigma)
#define CHUNK 8192
// requires N <= 131072 (src fits 24 bits after <<8 shift; bucket count <= 512)

// ---- init per-bucket cursors to fixed-capacity bases ----
__global__ void init_cur(int* __restrict__ cursor, int NB) {
    int i = blockIdx.x * blockDim.x + threadIdx.x;
    if (i < NB) cursor[i] = i * CAP;
}

// ---- bin edges by dst bucket; packed (src<<8)|(dst&255); dense reserved writes ----
__global__ __launch_bounds__(256) void bin_edges(
    const int* __restrict__ src, const int* __restrict__ dst,
    int* __restrict__ cursor, int* __restrict__ binned, int E, int NB)
{
    __shared__ int lh[512];
    __shared__ int lcur[512];
    int tid = threadIdx.x;
    for (int j = tid; j < NB; j += 256) lh[j] = 0;
    __syncthreads();
    int e0 = blockIdx.x * CHUNK;
    int ee = min(e0 + CHUNK, E);
    for (int i = e0 + tid; i < ee; i += 256) atomicAdd(&lh[dst[i] >> BSH], 1);
    __syncthreads();
    for (int j = tid; j < NB; j += 256) {
        int c = lh[j];
        if (c) lcur[j] = atomicAdd(&cursor[j], c);  // reserve contiguous range
    }
    __syncthreads();
    for (int i = e0 + tid; i < ee; i += 256) {
        int d = dst[i];
        int p = atomicAdd(&lcur[d >> BSH], 1);      // LDS atomic -> global slot
        binned[p] = (src[i] << BSH) | (d & 255);
    }
}

// ---- per-bucket CSR: rowptr/rowcnt + within-bucket dst-sort of src; dis ----
__global__ __launch_bounds__(256) void bucket_csr(
    const int* __restrict__ cursor, const int* __restrict__ binned,
    int* __restrict__ rowptr, int* __restrict__ rowcnt, int* __restrict__ sorted_src,
    float* __restrict__ dis, int N)
{
    __shared__ int cnt[256];
    __shared__ int s[256];
    __shared__ int lcur[256];
    int b = blockIdx.x, tid = threadIdx.x;
    int bn = b << BSH;
    cnt[tid] = 0;
    __syncthreads();
    int es = b * CAP, ee = cursor[b];
    for (int i = es + tid; i < ee; i += 256) atomicAdd(&cnt[binned[i] & 255], 1);
    __syncthreads();
    int v = cnt[tid];
    s[tid] = v;
    __syncthreads();
    for (int off = 1; off < 256; off <<= 1) {
        int t = (tid >= off) ? s[tid - off] : 0;
        __syncthreads();
        s[tid] += t;
        __syncthreads();
    }
    int ex = s[tid] - v;   // exclusive scan
    lcur[tid] = ex;
    int n = bn + tid;
    if (n < N) {
        rowptr[n] = es + ex;
        rowcnt[n] = v;
        dis[n] = rsqrtf((float)(v + 1));
    }
    __syncthreads();
    // scatter src into this bucket's contiguous range (single-WG-owned lines)
    for (int i = es + tid; i < ee; i += 256) {
        int e = binned[i];
        int p = atomicAdd(&lcur[e & 255], 1);
        sorted_src[es + p] = e >> BSH;
    }
}

// ---- h0 = x@We + be ; g1 = bf16(dis * (h0@W1)) ----
__global__ __launch_bounds__(256) void embed_g1(
    const float* __restrict__ x, const float* __restrict__ We,
    const float* __restrict__ be, const float* __restrict__ W1,
    const float* __restrict__ dis, float* __restrict__ h0,
    __hip_bfloat16* __restrict__ g, int N)
{
    __shared__ float sWe[NF * H];
    __shared__ float sW1[H * H];
    __shared__ float sbe[H];
    __shared__ float sx[8][NF];
    __shared__ float sh[8][H];

    int tid = threadIdx.x;
    for (int j = tid; j < NF * H; j += 256) sWe[j] = We[j];
    for (int j = tid; j < H * H; j += 256) sW1[j] = W1[j];
    if (tid < H) sbe[tid] = be[tid];

    int grp = tid >> 5, t = tid & 31;
    int node = blockIdx.x * 8 + grp;
    int nodec = node < N ? node : N - 1;
    if (t < NF) sx[grp][t] = x[(size_t)nodec * NF + t];
    __syncthreads();

    float h = sbe[t];
#pragma unroll
    for (int k = 0; k < NF; k++) h += sx[grp][k] * sWe[k * H + t];
    sh[grp][t] = h;
    __syncthreads();

    float gv = 0.f;
#pragma unroll
    for (int k = 0; k < H; k++) gv += sh[grp][k] * sW1[k * H + t];
    gv *= dis[nodec];

    if (node < N) {
        size_t o = (size_t)node * H + t;
        h0[o] = h;
        g[o] = __float2bfloat16(gv);
    }
}

// ---- atomic-free node-parallel aggregation: acc[d] = g[d] + sum g[src] ----
__global__ __launch_bounds__(256) void gather_agg(
    const int* __restrict__ rowptr, const int* __restrict__ rowcnt,
    const int* __restrict__ sorted_src,
    const __hip_bfloat16* __restrict__ g, float* __restrict__ acc, int N)
{
    int gid = blockIdx.x * blockDim.x + threadIdx.x;
    int node = gid >> 5;
    if (node >= N) return;
    int c = gid & 31;
    int start = rowptr[node];
    int end = start + rowcnt[node];
    float a = __bfloat162float(g[(size_t)node * H + c]);  // self-loop term
    int i = start;
    for (; i + 3 < end; i += 4) {
        int s0 = sorted_src[i], s1 = sorted_src[i + 1];
        int s2 = sorted_src[i + 2], s3 = sorted_src[i + 3];
        a += __bfloat162float(g[(size_t)s0 * H + c]);
        a += __bfloat162float(g[(size_t)s1 * H + c]);
        a += __bfloat162float(g[(size_t)s2 * H + c]);
        a += __bfloat162float(g[(size_t)s3 * H + c]);
    }
    for (; i < end; i++) a += __bfloat162float(g[(size_t)sorted_src[i] * H + c]);
    acc[(size_t)node * H + c] = a;
}

// ---- r1 = relu(dis*acc + b1); g2 = bf16(dis * ([r1,h0]@W2)) ----
__global__ __launch_bounds__(256) void mid_g2(
    const float* __restrict__ W2, const float* __restrict__ b1,
    const float* __restrict__ dis, const float* __restrict__ h0,
    __hip_bfloat16* __restrict__ g, const float* __restrict__ acc, int N)
{
    __shared__ float sW2[2 * H * H];
    __shared__ float sb1[H];
    __shared__ float srow[8][2 * H];

    int tid = threadIdx.x;
    for (int j = tid; j < 2 * H * H; j += 256) sW2[j] = W2[j];
    if (tid < H) sb1[tid] = b1[tid];
    __syncthreads();

    int grp = tid >> 5, t = tid & 31;
    int node = blockIdx.x * 8 + grp;
    int nodec = node < N ? node : N - 1;
    size_t o = (size_t)nodec * H + t;

    float di = dis[nodec];
    float r = fmaxf(di * acc[o] + sb1[t], 0.f);
    srow[grp][t] = r;
    srow[grp][H + t] = h0[o];
    __syncthreads();

    float gv = 0.f;
#pragma unroll
    for (int k = 0; k < 2 * H; k++) gv += srow[grp][k] * sW2[k * H + t];
    gv *= di;

    if (node < N) g[(size_t)node * H + t] = __float2bfloat16(gv);
}

// ---- out = relu([relu(dis*acc+b2), h0] @ Wp + bp + x[:,1]) ----
__global__ __launch_bounds__(256) void final_pred(
    const float* __restrict__ acc, const float* __restrict__ h0,
    const float* __restrict__ dis, const float* __restrict__ b2,
    const float* __restrict__ Wp, const float* __restrict__ bp,
    const float* __restrict__ x, float* __restrict__ out, int N)
{
    int i = blockIdx.x * blockDim.x + threadIdx.x;
    if (i >= N) return;
    float di = dis[i];
    float a = bp[0] + x[(size_t)i * NF + 1];
    size_t o = (size_t)i * H;
#pragma unroll
    for (int c = 0; c < H; c++)
        a += fmaxf(di * acc[o + c] + b2[c], 0.f) * Wp[c];
#pragma unroll
    for (int c = 0; c < H; c++)
        a += h0[o + c] * Wp[H + c];
    out[i] = fmaxf(a, 0.f);
}

extern "C" void kernel_launch(void* const* d_in, const int* in_sizes, int n_in,
                              void* d_out, int out_size, void* d_ws, size_t ws_size,
                              hipStream_t stream) {
    const float* x  = (const float*)d_in[0];
    const int*   ei = (const int*)d_in[1];
    const float* We = (const float*)d_in[2];
    const float* be = (const float*)d_in[3];
    const float* W1 = (const float*)d_in[4];
    const float* b1 = (const float*)d_in[5];
    const float* W2 = (const float*)d_in[6];
    const float* b2 = (const float*)d_in[7];
    const float* Wp = (const float*)d_in[8];
    const float* bp = (const float*)d_in[9];
    float* out = (float*)d_out;

    const int N = in_sizes[0] / NF;
    const int E = in_sizes[1] / 2;
    const int* src = ei;
    const int* dst = ei + E;
    const int NB = (N + 255) >> BSH;              // 391
    const int nchunk = (E + CHUNK - 1) / CHUNK;   // 196

    // workspace layout (ws ~= 256 MiB per fillBuffer WRITE_SIZE; we use ~60 MB)
    size_t Np  = ((size_t)N + 127) & ~(size_t)127;
    size_t NHp = ((size_t)N * H + 127) & ~(size_t)127;
    float* ws  = (float*)d_ws;
    float* dis = ws;                      // Np
    float* h0  = dis + Np;                // NHp
    float* acc = h0 + NHp;                // NHp
    __hip_bfloat16* g = (__hip_bfloat16*)(acc + NHp);  // NHp bf16
    int* cursor     = (int*)(g + NHp);    // 512
    int* rowptr     = cursor + 512;       // Np
    int* rowcnt     = rowptr + Np;        // Np
    int* binned     = rowcnt + Np;        // NB*CAP
    int* sorted_src = binned + (size_t)NB * CAP;  // NB*CAP

    init_cur<<<2, 256, 0, stream>>>(cursor, NB);
    bin_edges<<<nchunk, 256, 0, stream>>>(src, dst, cursor, binned, E, NB);
    bucket_csr<<<NB, 256, 0, stream>>>(cursor, binned, rowptr, rowcnt, sorted_src, dis, N);

    embed_g1<<<(N + 7) / 8, 256, 0, stream>>>(x, We, be, W1, dis, h0, g, N);
    gather_agg<<<((size_t)N * 32 + 255) / 256, 256, 0, stream>>>(rowptr, rowcnt, sorted_src, g, acc, N);
    mid_g2<<<(N + 7) / 8, 256, 0, stream>>>(W2, b1, dis, h0, g, acc, N);
    gather_agg<<<((size_t)N * 32 + 255) / 256, 256, 0, stream>>>(rowptr, rowcnt, sorted_src, g, acc, N);
    final_pred<<<(N + 255) / 256, 256, 0, stream>>>(acc, h0, dis, b2, Wp, bp, x, out, N);
}

// Round 8
// 252.387 us; speedup vs baseline: 3.4620x; 1.0242x over previous
//
#include <hip/hip_runtime.h>
#include <hip/hip_bf16.h>

#define NF 22     // node features
#define H  32     // hidden dim
#define BSH 8     // 256 nodes per bucket
#define CAP 8192  // edge capacity per bucket (mean 4092 at E=1.6M, NB=391)
#define CHUNK 2048
// requires N <= 131072 (src fits 24 bits after <<8 shift; bucket count <= 512)

// ---- init per-bucket cursors to fixed-capacity bases ----
__global__ void init_cur(int* __restrict__ cursor, int NB) {
    int i = blockIdx.x * blockDim.x + threadIdx.x;
    if (i < NB) cursor[i] = i * CAP;
}

// ---- bin edges by dst bucket; packed (src<<8)|(dst&255); dense reserved writes ----
__global__ __launch_bounds__(256) void bin_edges(
    const int* __restrict__ src, const int* __restrict__ dst,
    int* __restrict__ cursor, int* __restrict__ binned, int E, int NB)
{
    __shared__ int lh[512];
    __shared__ int lcur[512];
    int tid = threadIdx.x;
    for (int j = tid; j < NB; j += 256) lh[j] = 0;
    __syncthreads();
    int e0 = blockIdx.x * CHUNK;
    int ee = min(e0 + CHUNK, E);
    for (int i = e0 + tid; i < ee; i += 256) atomicAdd(&lh[dst[i] >> BSH], 1);
    __syncthreads();
    for (int j = tid; j < NB; j += 256) {
        int c = lh[j];
        if (c) lcur[j] = atomicAdd(&cursor[j], c);  // reserve contiguous range
    }
    __syncthreads();
    for (int i = e0 + tid; i < ee; i += 256) {
        int d = dst[i];
        int p = atomicAdd(&lcur[d >> BSH], 1);      // LDS atomic -> global slot
        binned[p] = (src[i] << BSH) | (d & 255);
    }
}

// ---- per-bucket CSR: rowptr/rowcnt + within-bucket dst-sort of src; dis ----
__global__ __launch_bounds__(256) void bucket_csr(
    const int* __restrict__ cursor, const int* __restrict__ binned,
    int* __restrict__ rowptr, int* __restrict__ rowcnt, int* __restrict__ sorted_src,
    float* __restrict__ dis, int N)
{
    __shared__ int cnt[256];
    __shared__ int s[256];
    __shared__ int lcur[256];
    int b = blockIdx.x, tid = threadIdx.x;
    int bn = b << BSH;
    cnt[tid] = 0;
    __syncthreads();
    int es = b * CAP, ee = cursor[b];
    for (int i = es + tid; i < ee; i += 256) atomicAdd(&cnt[binned[i] & 255], 1);
    __syncthreads();
    int v = cnt[tid];
    s[tid] = v;
    __syncthreads();
    for (int off = 1; off < 256; off <<= 1) {
        int t = (tid >= off) ? s[tid - off] : 0;
        __syncthreads();
        s[tid] += t;
        __syncthreads();
    }
    int ex = s[tid] - v;   // exclusive scan
    lcur[tid] = ex;
    int n = bn + tid;
    if (n < N) {
        rowptr[n] = es + ex;
        rowcnt[n] = v;
        dis[n] = rsqrtf((float)(v + 1));
    }
    __syncthreads();
    // scatter src into this bucket's contiguous range (single-WG-owned lines)
    for (int i = es + tid; i < ee; i += 256) {
        int e = binned[i];
        int p = atomicAdd(&lcur[e & 255], 1);
        sorted_src[es + p] = e >> BSH;
    }
}

// ---- h0 = x@We + be ; g1 = bf16(dis * (h0@W1)) ----
__global__ __launch_bounds__(256) void embed_g1(
    const float* __restrict__ x, const float* __restrict__ We,
    const float* __restrict__ be, const float* __restrict__ W1,
    const float* __restrict__ dis, float* __restrict__ h0,
    __hip_bfloat16* __restrict__ g, int N)
{
    __shared__ float sWe[NF * H];
    __shared__ float sW1[H * H];
    __shared__ float sbe[H];
    __shared__ float sx[8][NF];
    __shared__ float sh[8][H];

    int tid = threadIdx.x;
    for (int j = tid; j < NF * H; j += 256) sWe[j] = We[j];
    for (int j = tid; j < H * H; j += 256) sW1[j] = W1[j];
    if (tid < H) sbe[tid] = be[tid];

    int grp = tid >> 5, t = tid & 31;
    int node = blockIdx.x * 8 + grp;
    int nodec = node < N ? node : N - 1;
    if (t < NF) sx[grp][t] = x[(size_t)nodec * NF + t];
    __syncthreads();

    float h = sbe[t];
#pragma unroll
    for (int k = 0; k < NF; k++) h += sx[grp][k] * sWe[k * H + t];
    sh[grp][t] = h;
    __syncthreads();

    float gv = 0.f;
#pragma unroll
    for (int k = 0; k < H; k++) gv += sh[grp][k] * sW1[k * H + t];
    gv *= dis[nodec];

    if (node < N) {
        size_t o = (size_t)node * H + t;
        h0[o] = h;
        g[o] = __float2bfloat16(gv);
    }
}

// ---- fused gather #1 + mid layer: a = g1[d]+sum g1[src]; r1 = relu(dis*a+b1);
//      g2 = bf16(dis * ([r1,h0] @ W2)) ----
__global__ __launch_bounds__(256) void agg_mid(
    const int* __restrict__ rowptr, const int* __restrict__ rowcnt,
    const int* __restrict__ sorted_src,
    const __hip_bfloat16* __restrict__ g_in, const float* __restrict__ h0,
    const float* __restrict__ dis, const float* __restrict__ W2,
    const float* __restrict__ b1, __hip_bfloat16* __restrict__ g_out, int N)
{
    __shared__ float sW2[2 * H * H];
    __shared__ float srow[8][2 * H];

    int tid = threadIdx.x;
    for (int j = tid; j < 2 * H * H; j += 256) sW2[j] = W2[j];

    int grp = tid >> 5, c = tid & 31;
    int node = blockIdx.x * 8 + grp;
    int nodec = node < N ? node : N - 1;
    size_t o = (size_t)nodec * H + c;

    int start = rowptr[nodec];
    int end = start + rowcnt[nodec];
    float a = __bfloat162float(g_in[o]);  // self-loop
    int i = start;
    for (; i + 3 < end; i += 4) {
        int s0 = sorted_src[i], s1 = sorted_src[i + 1];
        int s2 = sorted_src[i + 2], s3 = sorted_src[i + 3];
        a += __bfloat162float(g_in[(size_t)s0 * H + c]);
        a += __bfloat162float(g_in[(size_t)s1 * H + c]);
        a += __bfloat162float(g_in[(size_t)s2 * H + c]);
        a += __bfloat162float(g_in[(size_t)s3 * H + c]);
    }
    for (; i < end; i++) a += __bfloat162float(g_in[(size_t)sorted_src[i] * H + c]);

    float di = dis[nodec];
    float r = fmaxf(di * a + b1[c], 0.f);   // b1 from global: no pre-barrier LDS read
    srow[grp][c] = r;
    srow[grp][H + c] = h0[o];
    __syncthreads();   // covers sW2 staging AND srow writes

    float gv = 0.f;
#pragma unroll
    for (int k = 0; k < 2 * H; k++) gv += srow[grp][k] * sW2[k * H + c];
    gv *= di;

    if (node < N) g_out[o] = __float2bfloat16(gv);
}

// ---- fused gather #2 + prediction head: a = g2[d]+sum g2[src];
//      out = relu( sum_c[ relu(dis*a+b2)*Wp_c + h0*Wp_{32+c} ] + bp + x[:,1] ) ----
__global__ __launch_bounds__(256) void agg_final(
    const int* __restrict__ rowptr, const int* __restrict__ rowcnt,
    const int* __restrict__ sorted_src,
    const __hip_bfloat16* __restrict__ g_in, const float* __restrict__ h0,
    const float* __restrict__ dis, const float* __restrict__ b2,
    const float* __restrict__ Wp, const float* __restrict__ bp,
    const float* __restrict__ x, float* __restrict__ out, int N)
{
    int gid = blockIdx.x * blockDim.x + threadIdx.x;
    int node = gid >> 5;
    if (node >= N) return;
    int c = gid & 31;
    size_t o = (size_t)node * H + c;

    int start = rowptr[node];
    int end = start + rowcnt[node];
    float a = __bfloat162float(g_in[o]);  // self-loop
    int i = start;
    for (; i + 3 < end; i += 4) {
        int s0 = sorted_src[i], s1 = sorted_src[i + 1];
        int s2 = sorted_src[i + 2], s3 = sorted_src[i + 3];
        a += __bfloat162float(g_in[(size_t)s0 * H + c]);
        a += __bfloat162float(g_in[(size_t)s1 * H + c]);
        a += __bfloat162float(g_in[(size_t)s2 * H + c]);
        a += __bfloat162float(g_in[(size_t)s3 * H + c]);
    }
    for (; i < end; i++) a += __bfloat162float(g_in[(size_t)sorted_src[i] * H + c]);

    float di = dis[node];
    float v = fmaxf(di * a + b2[c], 0.f) * Wp[c] + h0[o] * Wp[H + c];
#pragma unroll
    for (int off = 16; off > 0; off >>= 1) v += __shfl_down(v, off, 32);
    if (c == 0) out[node] = fmaxf(v + bp[0] + x[(size_t)node * NF + 1], 0.f);
}

extern "C" void kernel_launch(void* const* d_in, const int* in_sizes, int n_in,
                              void* d_out, int out_size, void* d_ws, size_t ws_size,
                              hipStream_t stream) {
    const float* x  = (const float*)d_in[0];
    const int*   ei = (const int*)d_in[1];
    const float* We = (const float*)d_in[2];
    const float* be = (const float*)d_in[3];
    const float* W1 = (const float*)d_in[4];
    const float* b1 = (const float*)d_in[5];
    const float* W2 = (const float*)d_in[6];
    const float* b2 = (const float*)d_in[7];
    const float* Wp = (const float*)d_in[8];
    const float* bp = (const float*)d_in[9];
    float* out = (float*)d_out;

    const int N = in_sizes[0] / NF;
    const int E = in_sizes[1] / 2;
    const int* src = ei;
    const int* dst = ei + E;
    const int NB = (N + 255) >> BSH;              // 391
    const int nchunk = (E + CHUNK - 1) / CHUNK;   // 782

    // workspace layout
    size_t Np  = ((size_t)N + 127) & ~(size_t)127;
    size_t NHp = ((size_t)N * H + 127) & ~(size_t)127;
    float* ws  = (float*)d_ws;
    float* dis = ws;                      // Np
    float* h0  = dis + Np;                // NHp
    __hip_bfloat16* g1 = (__hip_bfloat16*)(h0 + NHp);  // NHp bf16
    __hip_bfloat16* g2 = g1 + NHp;                     // NHp bf16
    int* cursor     = (int*)(g2 + NHp);   // 512
    int* rowptr     = cursor + 512;       // Np
    int* rowcnt     = rowptr + Np;        // Np
    int* binned     = rowcnt + Np;        // NB*CAP
    int* sorted_src = binned + (size_t)NB * CAP;  // NB*CAP

    init_cur<<<2, 256, 0, stream>>>(cursor, NB);
    bin_edges<<<nchunk, 256, 0, stream>>>(src, dst, cursor, binned, E, NB);
    bucket_csr<<<NB, 256, 0, stream>>>(cursor, binned, rowptr, rowcnt, sorted_src, dis, N);

    embed_g1<<<(N + 7) / 8, 256, 0, stream>>>(x, We, be, W1, dis, h0, g1, N);
    agg_mid<<<(N + 7) / 8, 256, 0, stream>>>(rowptr, rowcnt, sorted_src, g1, h0, dis, W2, b1, g2, N);
    agg_final<<<((size_t)N * 32 + 255) / 256, 256, 0, stream>>>(rowptr, rowcnt, sorted_src, g2, h0, dis, b2, Wp, bp, x, out, N);
}

// Round 9
// 222.880 us; speedup vs baseline: 3.9203x; 1.1324x over previous
//
#include <hip/hip_runtime.h>
#include <hip/hip_bf16.h>

#define NF 22     // node features
#define H  32     // hidden dim
#define BSH 8     // 256 nodes per bucket
#define CAP 8192  // edge capacity per bucket (mean 4092 at E=1.6M, NB=391; +64 sigma)
#define CHUNK 2048
// requires N <= 131072 (src fits 24 bits after <<8 shift; bucket count <= 512)

__device__ __forceinline__ float bflo(unsigned int v) { return __uint_as_float(v << 16); }
__device__ __forceinline__ float bfhi(unsigned int v) { return __uint_as_float(v & 0xffff0000u); }

// ---- init per-bucket cursors to fixed-capacity bases ----
__global__ void init_cur(int* __restrict__ cursor, int NB) {
    int i = blockIdx.x * blockDim.x + threadIdx.x;
    if (i < NB) cursor[i] = i * CAP;
}

// ---- bin edges by dst bucket; packed (src<<8)|(dst&255); dense reserved writes ----
__global__ __launch_bounds__(256) void bin_edges(
    const int* __restrict__ src, const int* __restrict__ dst,
    int* __restrict__ cursor, int* __restrict__ binned, int E, int NB)
{
    __shared__ int lh[512];
    __shared__ int lcur[512];
    int tid = threadIdx.x;
    for (int j = tid; j < NB; j += 256) lh[j] = 0;
    __syncthreads();
    int e0 = blockIdx.x * CHUNK;
    int ee = min(e0 + CHUNK, E);
    for (int i = e0 + tid; i < ee; i += 256) atomicAdd(&lh[dst[i] >> BSH], 1);
    __syncthreads();
    for (int j = tid; j < NB; j += 256) {
        int c = lh[j];
        if (c) lcur[j] = atomicAdd(&cursor[j], c);  // reserve contiguous range
    }
    __syncthreads();
    for (int i = e0 + tid; i < ee; i += 256) {
        int d = dst[i];
        int p = atomicAdd(&lcur[d >> BSH], 1);      // LDS atomic -> global slot
        binned[p] = (src[i] << BSH) | (d & 255);
    }
}

// ---- per-bucket CSR: rowptr/rowcnt + within-bucket dst-sort of src; dis ----
// 1024 threads: only 391 WGs exist, so fatten each one (R5 lesson: TLP per CU).
__global__ __launch_bounds__(1024) void bucket_csr(
    const int* __restrict__ cursor, const int* __restrict__ binned,
    int* __restrict__ rowptr, int* __restrict__ rowcnt, int* __restrict__ sorted_src,
    float* __restrict__ dis, int N)
{
    __shared__ int cnt[256];
    __shared__ int s[256];
    __shared__ int lcur[256];
    int b = blockIdx.x, tid = threadIdx.x;
    int bn = b << BSH;
    if (tid < 256) cnt[tid] = 0;
    __syncthreads();
    int es = b * CAP, ee = cursor[b];
    for (int i = es + tid; i < ee; i += 1024) atomicAdd(&cnt[binned[i] & 255], 1);
    __syncthreads();
    int v = 0;
    if (tid < 256) { v = cnt[tid]; s[tid] = v; }
    __syncthreads();
    for (int off = 1; off < 256; off <<= 1) {
        int t = 0;
        if (tid < 256 && tid >= off) t = s[tid - off];
        __syncthreads();
        if (tid < 256) s[tid] += t;
        __syncthreads();
    }
    if (tid < 256) {
        int ex = s[tid] - v;   // exclusive scan
        lcur[tid] = ex;
        int n = bn + tid;
        if (n < N) {
            rowptr[n] = es + ex;
            rowcnt[n] = v;
            dis[n] = rsqrtf((float)(v + 1));
        }
    }
    __syncthreads();
    // scatter src into this bucket's contiguous range (single-WG-owned lines)
    for (int i = es + tid; i < ee; i += 1024) {
        int e = binned[i];
        int p = atomicAdd(&lcur[e & 255], 1);
        sorted_src[es + p] = e >> BSH;
    }
}

// ---- h0 = x@We + be ; g1 = bf16(dis * (h0@W1)) ----
__global__ __launch_bounds__(256) void embed_g1(
    const float* __restrict__ x, const float* __restrict__ We,
    const float* __restrict__ be, const float* __restrict__ W1,
    const float* __restrict__ dis, float* __restrict__ h0,
    __hip_bfloat16* __restrict__ g, int N)
{
    __shared__ float sWe[NF * H];
    __shared__ float sW1[H * H];
    __shared__ float sbe[H];
    __shared__ float sx[8][NF];
    __shared__ float sh[8][H];

    int tid = threadIdx.x;
    for (int j = tid; j < NF * H; j += 256) sWe[j] = We[j];
    for (int j = tid; j < H * H; j += 256) sW1[j] = W1[j];
    if (tid < H) sbe[tid] = be[tid];

    int grp = tid >> 5, t = tid & 31;
    int node = blockIdx.x * 8 + grp;
    int nodec = node < N ? node : N - 1;
    if (t < NF) sx[grp][t] = x[(size_t)nodec * NF + t];
    __syncthreads();

    float h = sbe[t];
#pragma unroll
    for (int k = 0; k < NF; k++) h += sx[grp][k] * sWe[k * H + t];
    sh[grp][t] = h;
    __syncthreads();

    float gv = 0.f;
#pragma unroll
    for (int k = 0; k < H; k++) gv += sh[grp][k] * sW1[k * H + t];
    gv *= dis[nodec];

    if (node < N) {
        size_t o = (size_t)node * H + t;
        h0[o] = h;
        g[o] = __float2bfloat16(gv);
    }
}

// ---- fused gather #1 + mid layer, 16 lanes/node, bf16x2 loads ----
__global__ __launch_bounds__(256) void agg_mid(
    const int* __restrict__ rowptr, const int* __restrict__ rowcnt,
    const int* __restrict__ sorted_src,
    const __hip_bfloat16* __restrict__ g_in, const float* __restrict__ h0,
    const float* __restrict__ dis, const float* __restrict__ W2,
    const float* __restrict__ b1, __hip_bfloat16* __restrict__ g_out, int N)
{
    __shared__ float sW2[2 * H * H];
    __shared__ float srow[16][2 * H];

    int tid = threadIdx.x;
    for (int j = tid; j < 2 * H * H; j += 256) sW2[j] = W2[j];

    int grp = tid >> 4, lane = tid & 15;
    int node = blockIdx.x * 16 + grp;
    int nodec = node < N ? node : N - 1;

    const unsigned int* gv = (const unsigned int*)g_in;
    unsigned int sv = gv[(size_t)nodec * 16 + lane];
    float ax = bflo(sv), ay = bfhi(sv);   // self-loop term, 2 cols/lane

    int start = rowptr[nodec];
    int end = start + rowcnt[nodec];
    int i = start;
    for (; i + 7 < end; i += 8) {
        int s0 = sorted_src[i],     s1 = sorted_src[i + 1];
        int s2 = sorted_src[i + 2], s3 = sorted_src[i + 3];
        int s4 = sorted_src[i + 4], s5 = sorted_src[i + 5];
        int s6 = sorted_src[i + 6], s7 = sorted_src[i + 7];
        unsigned int v0 = gv[(size_t)s0 * 16 + lane], v1 = gv[(size_t)s1 * 16 + lane];
        unsigned int v2 = gv[(size_t)s2 * 16 + lane], v3 = gv[(size_t)s3 * 16 + lane];
        unsigned int v4 = gv[(size_t)s4 * 16 + lane], v5 = gv[(size_t)s5 * 16 + lane];
        unsigned int v6 = gv[(size_t)s6 * 16 + lane], v7 = gv[(size_t)s7 * 16 + lane];
        ax += bflo(v0) + bflo(v1) + bflo(v2) + bflo(v3)
            + bflo(v4) + bflo(v5) + bflo(v6) + bflo(v7);
        ay += bfhi(v0) + bfhi(v1) + bfhi(v2) + bfhi(v3)
            + bfhi(v4) + bfhi(v5) + bfhi(v6) + bfhi(v7);
    }
    for (; i + 3 < end; i += 4) {
        int s0 = sorted_src[i],     s1 = sorted_src[i + 1];
        int s2 = sorted_src[i + 2], s3 = sorted_src[i + 3];
        unsigned int v0 = gv[(size_t)s0 * 16 + lane], v1 = gv[(size_t)s1 * 16 + lane];
        unsigned int v2 = gv[(size_t)s2 * 16 + lane], v3 = gv[(size_t)s3 * 16 + lane];
        ax += bflo(v0) + bflo(v1) + bflo(v2) + bflo(v3);
        ay += bfhi(v0) + bfhi(v1) + bfhi(v2) + bfhi(v3);
    }
    for (; i < end; i++) {
        unsigned int v = gv[(size_t)sorted_src[i] * 16 + lane];
        ax += bflo(v); ay += bfhi(v);
    }

    float di = dis[nodec];
    float2 bb = ((const float2*)b1)[lane];
    float r0 = fmaxf(di * ax + bb.x, 0.f);
    float r1 = fmaxf(di * ay + bb.y, 0.f);
    float2 hh = ((const float2*)h0)[(size_t)nodec * 16 + lane];
    srow[grp][2 * lane]         = r0;
    srow[grp][2 * lane + 1]     = r1;
    srow[grp][H + 2 * lane]     = hh.x;
    srow[grp][H + 2 * lane + 1] = hh.y;
    __syncthreads();   // covers sW2 staging AND srow writes

    const float2* sW2v = (const float2*)sW2;
    float o0 = 0.f, o1 = 0.f;
#pragma unroll
    for (int k = 0; k < 2 * H; k++) {
        float rv = srow[grp][k];
        float2 w = sW2v[k * 16 + lane];
        o0 += rv * w.x;
        o1 += rv * w.y;
    }
    o0 *= di; o1 *= di;

    if (node < N) {
        __hip_bfloat162 p;
        p.x = __float2bfloat16(o0);
        p.y = __float2bfloat16(o1);
        ((__hip_bfloat162*)g_out)[(size_t)node * 16 + lane] = p;
    }
}

// ---- fused gather #2 + prediction head, 16 lanes/node, bf16x2 loads ----
__global__ __launch_bounds__(256) void agg_final(
    const int* __restrict__ rowptr, const int* __restrict__ rowcnt,
    const int* __restrict__ sorted_src,
    const __hip_bfloat16* __restrict__ g_in, const float* __restrict__ h0,
    const float* __restrict__ dis, const float* __restrict__ b2,
    const float* __restrict__ Wp, const float* __restrict__ bp,
    const float* __restrict__ x, float* __restrict__ out, int N)
{
    int gid = blockIdx.x * blockDim.x + threadIdx.x;
    int node = gid >> 4;
    if (node >= N) return;
    int lane = gid & 15;

    const unsigned int* gv = (const unsigned int*)g_in;
    unsigned int sv = gv[(size_t)node * 16 + lane];
    float ax = bflo(sv), ay = bfhi(sv);

    int start = rowptr[node];
    int end = start + rowcnt[node];
    int i = start;
    for (; i + 7 < end; i += 8) {
        int s0 = sorted_src[i],     s1 = sorted_src[i + 1];
        int s2 = sorted_src[i + 2], s3 = sorted_src[i + 3];
        int s4 = sorted_src[i + 4], s5 = sorted_src[i + 5];
        int s6 = sorted_src[i + 6], s7 = sorted_src[i + 7];
        unsigned int v0 = gv[(size_t)s0 * 16 + lane], v1 = gv[(size_t)s1 * 16 + lane];
        unsigned int v2 = gv[(size_t)s2 * 16 + lane], v3 = gv[(size_t)s3 * 16 + lane];
        unsigned int v4 = gv[(size_t)s4 * 16 + lane], v5 = gv[(size_t)s5 * 16 + lane];
        unsigned int v6 = gv[(size_t)s6 * 16 + lane], v7 = gv[(size_t)s7 * 16 + lane];
        ax += bflo(v0) + bflo(v1) + bflo(v2) + bflo(v3)
            + bflo(v4) + bflo(v5) + bflo(v6) + bflo(v7);
        ay += bfhi(v0) + bfhi(v1) + bfhi(v2) + bfhi(v3)
            + bfhi(v4) + bfhi(v5) + bfhi(v6) + bfhi(v7);
    }
    for (; i + 3 < end; i += 4) {
        int s0 = sorted_src[i],     s1 = sorted_src[i + 1];
        int s2 = sorted_src[i + 2], s3 = sorted_src[i + 3];
        unsigned int v0 = gv[(size_t)s0 * 16 + lane], v1 = gv[(size_t)s1 * 16 + lane];
        unsigned int v2 = gv[(size_t)s2 * 16 + lane], v3 = gv[(size_t)s3 * 16 + lane];
        ax += bflo(v0) + bflo(v1) + bflo(v2) + bflo(v3);
        ay += bfhi(v0) + bfhi(v1) + bfhi(v2) + bfhi(v3);
    }
    for (; i < end; i++) {
        unsigned int v = gv[(size_t)sorted_src[i] * 16 + lane];
        ax += bflo(v); ay += bfhi(v);
    }

    float di = dis[node];
    float2 b2v = ((const float2*)b2)[lane];
    float2 wpa = ((const float2*)Wp)[lane];        // Wp[2l], Wp[2l+1]
    float2 wpb = ((const float2*)Wp)[16 + lane];   // Wp[32+2l], Wp[32+2l+1]
    float2 hh = ((const float2*)h0)[(size_t)node * 16 + lane];
    float v = fmaxf(di * ax + b2v.x, 0.f) * wpa.x
            + fmaxf(di * ay + b2v.y, 0.f) * wpa.y
            + hh.x * wpb.x + hh.y * wpb.y;
#pragma unroll
    for (int off = 8; off > 0; off >>= 1) v += __shfl_down(v, off, 16);
    if (lane == 0) out[node] = fmaxf(v + bp[0] + x[(size_t)node * NF + 1], 0.f);
}

extern "C" void kernel_launch(void* const* d_in, const int* in_sizes, int n_in,
                              void* d_out, int out_size, void* d_ws, size_t ws_size,
                              hipStream_t stream) {
    const float* x  = (const float*)d_in[0];
    const int*   ei = (const int*)d_in[1];
    const float* We = (const float*)d_in[2];
    const float* be = (const float*)d_in[3];
    const float* W1 = (const float*)d_in[4];
    const float* b1 = (const float*)d_in[5];
    const float* W2 = (const float*)d_in[6];
    const float* b2 = (const float*)d_in[7];
    const float* Wp = (const float*)d_in[8];
    const float* bp = (const float*)d_in[9];
    float* out = (float*)d_out;

    const int N = in_sizes[0] / NF;
    const int E = in_sizes[1] / 2;
    const int* src = ei;
    const int* dst = ei + E;
    const int NB = (N + 255) >> BSH;              // 391
    const int nchunk = (E + CHUNK - 1) / CHUNK;   // 782

    // workspace layout
    size_t Np  = ((size_t)N + 127) & ~(size_t)127;
    size_t NHp = ((size_t)N * H + 127) & ~(size_t)127;
    float* ws  = (float*)d_ws;
    float* dis = ws;                      // Np
    float* h0  = dis + Np;                // NHp
    __hip_bfloat16* g1 = (__hip_bfloat16*)(h0 + NHp);  // NHp bf16
    __hip_bfloat16* g2 = g1 + NHp;                     // NHp bf16
    int* cursor     = (int*)(g2 + NHp);   // 512
    int* rowptr     = cursor + 512;       // Np
    int* rowcnt     = rowptr + Np;        // Np
    int* binned     = rowcnt + Np;        // NB*CAP
    int* sorted_src = binned + (size_t)NB * CAP;  // NB*CAP

    init_cur<<<2, 256, 0, stream>>>(cursor, NB);
    bin_edges<<<nchunk, 256, 0, stream>>>(src, dst, cursor, binned, E, NB);
    bucket_csr<<<NB, 1024, 0, stream>>>(cursor, binned, rowptr, rowcnt, sorted_src, dis, N);

    embed_g1<<<(N + 7) / 8, 256, 0, stream>>>(x, We, be, W1, dis, h0, g1, N);
    agg_mid<<<(N + 15) / 16, 256, 0, stream>>>(rowptr, rowcnt, sorted_src, g1, h0, dis, W2, b1, g2, N);
    agg_final<<<((size_t)N * 16 + 255) / 256, 256, 0, stream>>>(rowptr, rowcnt, sorted_src, g2, h0, dis, b2, Wp, bp, x, out, N);
}